// Round 5
// baseline (27.109 us; speedup 1.0000x reference)
//
#include <hip/hip_runtime.h>

// Problem: B=4096, N=16, E=512. Outputs: aggregated (B,E) then weights (B,N), f32.
//
// task_anchor @ v_t is a per-b constant across the softmax axis -> dead input
// (softmax shift invariance). Traffic floor: 134.2 MB read + 8.9 MB write.
//
// Structure: one block (2 waves, 128 thr) per b. Wave w owns e-slice
// [256w, 256w+256); lane owns one float4 per row -> tile = 16 x float4 =
// 64 VGPRs; loads are dwordx4 (1 KB/wave/instr, coalescing sweet spot).
// Scores: per-lane dot4 partials, 17-shuffle multi-value butterfly,
// 128 B LDS cross-wave combine (2 waves only). Aggregation from the
// register tile -> expert read exactly once.

#define NB 4096
#define NEXP 16
#define EDIM 512

typedef float f32x4 __attribute__((ext_vector_type(4)));

__global__ __launch_bounds__(128, 4) void meta_attn_kernel(
    const float* __restrict__ expert,   // [B, 16, 512]
    const float* __restrict__ v,        // [640, 1]; v_e = v[0:512]
    float* __restrict__ out_agg,        // [B, 512]
    float* __restrict__ out_w)          // [B, 16]
{
    const int wave = threadIdx.x >> 6;
    const int lane = threadIdx.x & 63;
    const int b = blockIdx.x;

    const int eoff = 256 * wave + 4 * lane;            // this thread's e-offset
    const float* row = expert + (size_t)b * (NEXP * EDIM) + eoff;

    const f32x4 ve = *(const f32x4*)(v + eoff);

    // Register tile: this thread's float4 of every row (64 VGPRs)
    f32x4 tile[NEXP];
#pragma unroll
    for (int n = 0; n < NEXP; ++n)
        tile[n] = *(const f32x4*)(row + n * EDIM);

    // Per-lane partial dots over the 4 owned elements
    float cur[NEXP];
#pragma unroll
    for (int n = 0; n < NEXP; ++n)
        cur[n] = tile[n].x * ve.x + tile[n].y * ve.y
               + tile[n].z * ve.z + tile[n].w * ve.w;

    // Multi-value butterfly: reduce 16 partials over 64 lanes in 17 shuffles.
    // (same scheme as R4, verified) Lane ends owning score rev4(lane&15).
    float t8[8];
    {
        const bool hi = (lane & 1) != 0;
#pragma unroll
        for (int j = 0; j < 8; ++j) {
            const float send = hi ? cur[j] : cur[j + 8];
            const float keep = hi ? cur[j + 8] : cur[j];
            t8[j] = keep + __shfl_xor(send, 1, 64);
        }
    }
    float t4[4];
    {
        const bool hi = (lane & 2) != 0;
#pragma unroll
        for (int j = 0; j < 4; ++j) {
            const float send = hi ? t8[j] : t8[j + 4];
            const float keep = hi ? t8[j + 4] : t8[j];
            t4[j] = keep + __shfl_xor(send, 2, 64);
        }
    }
    float t2[2];
    {
        const bool hi = (lane & 4) != 0;
#pragma unroll
        for (int j = 0; j < 2; ++j) {
            const float send = hi ? t4[j] : t4[j + 2];
            const float keep = hi ? t4[j + 2] : t4[j];
            t2[j] = keep + __shfl_xor(send, 4, 64);
        }
    }
    float t1;
    {
        const bool hi = (lane & 8) != 0;
        const float send = hi ? t2[0] : t2[1];
        const float keep = hi ? t2[1] : t2[0];
        t1 = keep + __shfl_xor(send, 8, 64);
    }
    t1 += __shfl_xor(t1, 16, 64);
    t1 += __shfl_xor(t1, 32, 64);
    // lane now holds this wave's partial of score rev4(lane&15)

    // Cross-wave combine via 128 B LDS (2 waves)
    __shared__ float lds_s[NEXP][2];
    if (lane < 16) {
        const int idx = ((lane & 1) << 3) | ((lane & 2) << 1) |
                        ((lane & 4) >> 1) | ((lane & 8) >> 3);
        lds_s[idx][wave] = t1;
    }
    __syncthreads();

    float s[NEXP];
#pragma unroll
    for (int n = 0; n < NEXP; ++n)
        s[n] = lds_s[n][0] + lds_s[n][1];   // broadcast reads, conflict-free

    // Softmax over 16 scores (redundant per thread, no divergence)
    float mx = s[0];
#pragma unroll
    for (int n = 1; n < NEXP; ++n) mx = fmaxf(mx, s[n]);
    float w[NEXP];
    float sum = 0.0f;
#pragma unroll
    for (int n = 0; n < NEXP; ++n) {
        w[n] = __expf(s[n] - mx);
        sum += w[n];
    }
    const float inv = 1.0f / sum;
#pragma unroll
    for (int n = 0; n < NEXP; ++n) w[n] *= inv;

    // Aggregation from the register tile (no global re-read)
    f32x4 acc = {0.f, 0.f, 0.f, 0.f};
#pragma unroll
    for (int n = 0; n < NEXP; ++n)
        acc += w[n] * tile[n];
    *(f32x4*)(out_agg + (size_t)b * EDIM + eoff) = acc;

    // Weights: select chain (compile-time indices) + one coalesced 64 B store
    if (wave == 0) {
        float myw = w[0];
#pragma unroll
        for (int n = 1; n < NEXP; ++n) myw = (lane == n) ? w[n] : myw;
        if (lane < NEXP) out_w[(size_t)b * NEXP + lane] = myw;
    }
}

extern "C" void kernel_launch(void* const* d_in, const int* in_sizes, int n_in,
                              void* d_out, int out_size, void* d_ws, size_t ws_size,
                              hipStream_t stream) {
    // d_in: 0=scene_repr (unused), 1=task_anchor (unused), 2=expert_reprs, 3=v
    const float* expert = (const float*)d_in[2];
    const float* v      = (const float*)d_in[3];
    float* out_agg = (float*)d_out;
    float* out_w   = (float*)d_out + (size_t)NB * EDIM;

    meta_attn_kernel<<<dim3(NB), dim3(128), 0, stream>>>(expert, v, out_agg, out_w);
}